// Round 1
// baseline (76.283 us; speedup 1.0000x reference)
//
#include <hip/hip_runtime.h>

// One wavefront = one 9-qubit patch circuit. R8: FC layer FUSED into the
// patch kernel — each block (4 patches, always same batch since 676=169*4)
// exchanges its 12 feature values through LDS, then threads 0..9 dot 12
// CONTIGUOUS fc_w floats (3x float4) and atomicAdd one partial per class.
// d_out is zero-filled by a 320B hipMemsetAsync first (graph-capturable).
// This removes the fc_kernel dispatch and the 64KB feats round-trip
// through d_ws. Per-BLOCK atomics (13.5k total, 169/address) — not the
// per-patch scheme R2 rejected; no fences/spinning (R7 lesson).
//
// R7 lesson (268us disaster): per-block __threadfence + grid-wide
// last-block-done serializes L2 writebacks across 8 XCDs — a second launch
// is ~100x cheaper than grid-scope fencing. R4: 1 patch/wave (TLP > ILP).
// The 256MB d_ws poison fill (~40us) is fixed harness overhead.
//
// Qubit -> bit remap:
//   qubit 0 -> reg bit 0 (R0)  qubit 3 -> reg bit 1 (R1)  qubit 6 -> reg bit 2 (R2)
//   qubit 1 -> lane bit 0      qubit 2 -> lane bit 1      qubit 4 -> lane bit 2
//   qubit 5 -> lane bit 3      qubit 7 -> lane bit 4      qubit 8 -> lane bit 5
//
// Algebraic pipeline (all pieces correctness-proven in R6/R7):
//   enc RY + conv1 RY -> per-qubit (c,s); conv1 RZ folds into tau_q(b)
//   ring CNOT eliminated analytically (GF(2)-linear) -> per-lane product state
//   pool1 -> per-lane RX on each 2-vector factor (LUT by 2 lane bits)
//   conv2 single-qubit layer at factor level; RY(w34)RY(w36), RY(w35)RY(w37) folded
//   CX(0,3),CX(3,6),CX(6,0) folded into expansion indexing:
//     v(b0,b1,b2) = p0(b0^b2) * p1(b0^b1^b2) * p2(b1^b2)   (zero instructions)
//   then 8 param gates + CX(0,6); measure qubit0, ez = 2*P(even)-1.

__device__ __forceinline__ float shx(float v, int m) { return __shfl_xor(v, m, 64); }

__device__ __forceinline__ float2 cmul(float2 a, float2 b) {
  return make_float2(a.x * b.x - a.y * b.y, a.x * b.y + a.y * b.x);
}

// ---- full-state reg-qubit gates ----
template <int TM> __device__ __forceinline__
void ry_r(float (&re)[8], float (&im)[8], float c, float s) {
#pragma unroll
  for (int r0 = 0; r0 < 8; ++r0) if (!(r0 & TM)) {
    const int r1 = r0 | TM;
    float a = re[r0], bb = re[r1];
    re[r0] = c * a - s * bb; re[r1] = s * a + c * bb;
    a = im[r0]; bb = im[r1];
    im[r0] = c * a - s * bb; im[r1] = s * a + c * bb;
  }
}
template <int TM> __device__ __forceinline__
void rz_r(float (&re)[8], float (&im)[8], float c, float s) {
#pragma unroll
  for (int r = 0; r < 8; ++r) {
    const float sg = (r & TM) ? s : -s;
    const float a = re[r], bb = im[r];
    re[r] = c * a - sg * bb;
    im[r] = c * bb + sg * a;
  }
}
template <int CM, int TM> __device__ __forceinline__
void cx_rr(float (&re)[8], float (&im)[8]) {
#pragma unroll
  for (int r0 = 0; r0 < 8; ++r0) if ((r0 & CM) && !(r0 & TM)) {
    const int r1 = r0 | TM;
    float t = re[r0]; re[r0] = re[r1]; re[r1] = t;
    t = im[r0]; im[r0] = im[r1]; im[r1] = t;
  }
}
template <int CM, int TM> __device__ __forceinline__
void crx_rr(float (&re)[8], float (&im)[8], float co, float si) {
#pragma unroll
  for (int r0 = 0; r0 < 8; ++r0) if ((r0 & CM) && !(r0 & TM)) {
    const int r1 = r0 | TM;
    const float r0r = re[r0], r0i = im[r0], r1r = re[r1], r1i = im[r1];
    re[r0] = co * r0r + si * r1i; im[r0] = co * r0i - si * r1r;
    re[r1] = co * r1r + si * r0i; im[r1] = co * r1i - si * r0r;
  }
}

// ---- factor-level single-qubit gates on a complex 2-vector (A,B) ----
__device__ __forceinline__
void ry_f(float2& A, float2& B, float c, float s) {
  const float2 nA = make_float2(c * A.x - s * B.x, c * A.y - s * B.y);
  const float2 nB = make_float2(s * A.x + c * B.x, s * A.y + c * B.y);
  A = nA; B = nB;
}
__device__ __forceinline__
void rz_f(float2& A, float2& B, float c, float s) {
  A = make_float2(c * A.x + s * A.y, c * A.y - s * A.x);   // * e^{-i t/2}
  B = make_float2(c * B.x - s * B.y, c * B.y + s * B.x);   // * e^{+i t/2}
}
__device__ __forceinline__
void rx_f(float2& A, float2& B, float c, float s) {         // pool1 folded RX
  const float2 nA = make_float2(c * A.x + s * B.y, c * A.y - s * B.x);
  const float2 nB = make_float2(c * B.x + s * A.y, c * B.y - s * A.x);
  A = nA; B = nB;
}

__global__ __launch_bounds__(256) void qcnn_fused(const float* __restrict__ x,
                                                  const float* __restrict__ w,
                                                  const float* __restrict__ fc_w,
                                                  const float* __restrict__ fc_b,
                                                  float* __restrict__ out) {
  // per-wave LDS regions — no cross-wave sharing until the FC epilogue
  __shared__ float4 tauT[4][9];    // qubit q -> (t0r, t0i, t1r, t1i)
  __shared__ float2 rxT[4][12];    // pool1 RX LUT [axis][2 control bits]
  __shared__ float2 gT[4][16];     // folded gate params (cos, sin)
  __shared__ float sfeat[12];      // block's 4 patches x [X,Y,Z]

  const int tid = threadIdx.x;
  const int wv = tid >> 6, lane = tid & 63;
  const unsigned p = blockIdx.x * 4u + wv;           // patch id (grid exact)
  const unsigned b = p / 676u;
  const unsigned rem = p - b * 676u;
  const unsigned i = rem / 26u, j = rem - i * 26u;

  // ---- per-wave table build (lane roles; same-wave DS ordering) ----
  if (lane < 9) {
    const int di = lane / 3, dj = lane - di * 3;
    const float xv = x[b * 784u + (i + di) * 28u + (j + dj)];
    const float ang = fmaf(xv, 3.14159265358979323846f, w[lane]) * 0.5f;
    float s, c; __sincosf(ang, &s, &c);
    float zs, zc; __sincosf(0.5f * w[9 + lane], &zs, &zc);
    tauT[wv][lane] = make_float4(c * zc, -c * zs, s * zc, s * zs);
  } else if (lane < 21) {
    const int k = lane - 9, a = k >> 2, cb = k & 3;
    float th = 0.0f;
    if (cb & 1) th += w[18 + 2 * a];
    if (cb & 2) th += w[19 + 2 * a];
    float s, c; __sincosf(0.5f * th, &s, &c);
    rxT[wv][k] = make_float2(c, s);
  } else if (lane < 37) {
    const int k = lane - 21;
    float th;
    if (k < 10)       th = w[24 + k];            // w24..w33
    else if (k == 10) th = w[34] + w[36];        // folded RY q0
    else if (k == 11) th = w[35] + w[37];        // folded RY q6
    else              th = w[26 + k];            // w38..w41
    float s, c; __sincosf(0.5f * th, &s, &c);
    gT[wv][k] = make_float2(c, s);
  }

  const int l0 = lane & 1, l1 = (lane >> 1) & 1, l2 = (lane >> 2) & 1;
  const int l3 = (lane >> 3) & 1, l4 = (lane >> 4) & 1, l5 = (lane >> 5) & 1;

  float4 tq[9];
#pragma unroll
  for (int q = 0; q < 9; ++q) tq[q] = tauT[wv][q];
  auto tau = [&](int bit, int q) -> float2 {
    const float4 t = tq[q];
    return bit ? make_float2(t.z, t.w) : make_float2(t.x, t.y);
  };

  // post-ring product-state factors (derivation verified R6/R7)
  const int a0 = l5, a1 = l0 ^ l5;
  float2 p00 = cmul(tau(a0, 0), tau(a1, 1));
  float2 p01 = cmul(tau(a0 ^ 1, 0), tau(a1 ^ 1, 1));
  float2 p10 = cmul(tau(l1, 3), tau(l2, 4));
  float2 p11 = cmul(tau(l1 ^ 1, 3), tau(l2 ^ 1, 4));
  float2 p20 = cmul(tau(l3, 6), tau(l4, 7));
  float2 p21 = cmul(tau(l3 ^ 1, 6), tau(l4 ^ 1, 7));
  const float2 T = cmul(cmul(tau(l0 ^ l1, 2), tau(l2 ^ l3, 5)), tau(l4 ^ l5, 8));
  p20 = cmul(p20, T);
  p21 = cmul(p21, T);

  // pool1: per-lane RX on each factor
  {
    const float2 x0 = rxT[wv][lane & 3];
    const float2 x1 = rxT[wv][4 + ((lane >> 2) & 3)];
    const float2 x2 = rxT[wv][8 + ((lane >> 4) & 3)];
    rx_f(p00, p01, x0.x, x0.y);
    rx_f(p10, p11, x1.x, x1.y);
    rx_f(p20, p21, x2.x, x2.y);
  }

  // conv2 single-qubit layer at FACTOR level (w24..w29)
  {
    const float2 g0 = gT[wv][0], g1 = gT[wv][1], g2 = gT[wv][2];
    const float2 g3 = gT[wv][3], g4 = gT[wv][4], g5 = gT[wv][5];
    ry_f(p00, p01, g0.x, g0.y);   // RY q0
    ry_f(p10, p11, g1.x, g1.y);   // RY q3
    ry_f(p20, p21, g2.x, g2.y);   // RY q6
    rz_f(p00, p01, g3.x, g3.y);   // RZ q0
    rz_f(p10, p11, g4.x, g4.y);   // RZ q3
    rz_f(p20, p21, g5.x, g5.y);   // RZ q6
  }

  // expand with CX(0,3),CX(3,6),CX(6,0) FOLDED into the index map:
  //   v(b0,b1,b2) = p0(b0^b2) * p1(b0^b1^b2) * p2(b1^b2)
  float re[8], im[8];
  {
    const float2 q00 = cmul(p00, p10);   // p0(0)p1(0)
    const float2 q01 = cmul(p00, p11);   // p0(0)p1(1)
    const float2 q10 = cmul(p01, p10);   // p0(1)p1(0)
    const float2 q11 = cmul(p01, p11);   // p0(1)p1(1)
    float2 u;
    u = cmul(q00, p20); re[0] = u.x; im[0] = u.y;   // r=0: p0(0)p1(0)p2(0)
    u = cmul(q11, p20); re[1] = u.x; im[1] = u.y;   // r=1: p0(1)p1(1)p2(0)
    u = cmul(q01, p21); re[2] = u.x; im[2] = u.y;   // r=2: p0(0)p1(1)p2(1)
    u = cmul(q10, p21); re[3] = u.x; im[3] = u.y;   // r=3: p0(1)p1(0)p2(1)
    u = cmul(q11, p21); re[4] = u.x; im[4] = u.y;   // r=4: p0(1)p1(1)p2(1)
    u = cmul(q00, p21); re[5] = u.x; im[5] = u.y;   // r=5: p0(0)p1(0)p2(1)
    u = cmul(q10, p20); re[6] = u.x; im[6] = u.y;   // r=6: p0(1)p1(0)p2(0)
    u = cmul(q01, p20); re[7] = u.x; im[7] = u.y;   // r=7: p0(0)p1(1)p2(0)
  }

  // remaining gates (post-CX-trio): 8 parametrized + CX(0,6)
  {
    const float2 g6 = gT[wv][6],  g7 = gT[wv][7],  g8 = gT[wv][8];
    const float2 g9 = gT[wv][9],  gA = gT[wv][10], gB = gT[wv][11];
    const float2 gC = gT[wv][12], gD = gT[wv][13], gE = gT[wv][14];
    const float2 gF = gT[wv][15];
    ry_r<1>(re, im, g6.x, g6.y);         // RY q0 w30
    rz_r<2>(re, im, g7.x, g7.y);         // RZ q3 w31
    crx_rr<2, 1>(re, im, g8.x, g8.y);    // CRX(3,0) w32
    crx_rr<2, 4>(re, im, g9.x, g9.y);    // CRX(3,6) w33
    ry_r<1>(re, im, gA.x, gA.y);         // RY q0 (w34+w36)
    ry_r<4>(re, im, gB.x, gB.y);         // RY q6 (w35+w37)
    cx_rr<1, 4>(re, im);                 // CX(0,6)
    rz_r<1>(re, im, gC.x, gC.y);         // RZ q0 w38
    rz_r<4>(re, im, gD.x, gD.y);         // RZ q6 w39
    crx_rr<4, 1>(re, im, gE.x, gE.y);    // CRX(6,0) w40
    ry_r<1>(re, im, gF.x, gF.y);         // RY q0 w41
  }

  // <X>,<Y>,<Z> on qubit 0 (reg bit 0); ez = 2*P(even)-1
  float zr = 0.f, zi = 0.f, pe = 0.f;
#pragma unroll
  for (int r0 = 0; r0 < 8; r0 += 2) {
    const int r1 = r0 + 1;
    zr += re[r0] * re[r1] + im[r0] * im[r1];
    zi += re[r0] * im[r1] - im[r0] * re[r1];
    pe += re[r0] * re[r0] + im[r0] * im[r0];
  }
#pragma unroll
  for (int m = 1; m < 64; m <<= 1) { zr += shx(zr, m); zi += shx(zi, m); pe += shx(pe, m); }

  if (lane == 0) {
    sfeat[wv * 3 + 0] = 2.0f * zr;
    sfeat[wv * 3 + 1] = 2.0f * zi;
    sfeat[wv * 3 + 2] = 2.0f * pe - 1.0f;
  }

  // ---- fused FC epilogue: one 12-wide dot + atomicAdd per class ----
  __syncthreads();
  if (tid < 10) {
    const int c = tid;
    const unsigned bb = blockIdx.x / 169u;           // batch (676 = 169*4)
    const unsigned lb = blockIdx.x - bb * 169u;      // block-in-batch
    const unsigned base_col = lb * 12u;              // contiguous 12 cols, 16B aligned
    const float4* wp = reinterpret_cast<const float4*>(fc_w + c * 2028u + base_col);
    const float4 w0 = wp[0], w1 = wp[1], w2 = wp[2];
    float acc = w0.x * sfeat[0] + w0.y * sfeat[1] + w0.z * sfeat[2] + w0.w * sfeat[3];
    acc      += w1.x * sfeat[4] + w1.y * sfeat[5] + w1.z * sfeat[6] + w1.w * sfeat[7];
    acc      += w2.x * sfeat[8] + w2.y * sfeat[9] + w2.z * sfeat[10] + w2.w * sfeat[11];
    if (lb == 0) acc += fc_b[c];                     // bias added once per batch row
    atomicAdd(&out[bb * 10u + c], acc);
  }
}

extern "C" void kernel_launch(void* const* d_in, const int* in_sizes, int n_in,
                              void* d_out, int out_size, void* d_ws, size_t ws_size,
                              hipStream_t stream) {
  const float* x    = (const float*)d_in[0];   // (B,1,28,28)
  const float* w    = (const float*)d_in[1];   // (42,)
  const float* fc_w = (const float*)d_in[2];   // (10, 2028)
  const float* fc_b = (const float*)d_in[3];   // (10,)
  float* out = (float*)d_out;                  // (B, 10)

  const int B = in_sizes[0] / 784;             // 8
  const int npatch = B * 676;                  // 5408; divisible by 4

  hipMemsetAsync(out, 0, (size_t)(B * 10) * sizeof(float), stream);
  qcnn_fused<<<npatch / 4, 256, 0, stream>>>(x, w, fc_w, fc_b, out);
}

// Round 2
// 67.186 us; speedup vs baseline: 1.1354x; 1.1354x over previous
//
#include <hip/hip_runtime.h>

// One wavefront = one 9-qubit patch circuit; zero block-level barriers
// (per-wave LDS tables, wave-internal DS ordering). Two-kernel structure:
// feats -> d_ws, then a tiny FC kernel.
//
// R8 lesson (fused-FC regression, 76.3us): 13.5k atomicAdds into a 320B
// out buffer bounce 5 cache lines across 8 non-coherent XCD L2s — same
// coherence tax as R7's fence disaster. Two plain launches beat any
// cross-XCD fan-in. Dispatch-count itself is NOT the lever (R1 matched
// R0's dispatch count and still lost): the ~24us of non-fill non-kernel
// time is graph/launch overhead outside .cpp control.
// R7 lesson (268us disaster): grid-scope fencing serializes L2 writebacks.
// R2: no per-patch atomics. R4: 1 patch/wave (TLP > ILP).
// The 256MB d_ws poison fill (~40us @ 85% HBM peak) is fixed harness cost.
//
// R9 (this round) VALU cuts, all by Pauli/commutation algebra:
//  - RZ(q3,w31) DROPPED: diagonal on q3, commutes past CRX(3,0)/CRX(3,6)
//    (q3 = control); q3 never touched after; measurement acts on q0 only.
//  - RZ(q6,w39) DROPPED: commutes past CRX(6,0) (q6 = control); q6 then idle.
//  - Final RY(q0,w41) folded into the measurement basis (Bloch rotation
//    about Y applied to (ex,ez) in lane 0 post-reduction).
//  - fc_kernel: float4 loads (2028 = 507*4, rows 16B-aligned).
//
// Qubit -> bit remap:
//   qubit 0 -> reg bit 0 (R0)  qubit 3 -> reg bit 1 (R1)  qubit 6 -> reg bit 2 (R2)
//   qubit 1 -> lane bit 0      qubit 2 -> lane bit 1      qubit 4 -> lane bit 2
//   qubit 5 -> lane bit 3      qubit 7 -> lane bit 4      qubit 8 -> lane bit 5
//
// Algebraic pipeline (pieces correctness-proven in R6/R7):
//   enc RY + conv1 RY -> per-qubit (c,s); conv1 RZ folds into tau_q(b)
//   ring CNOT eliminated analytically (GF(2)-linear) -> per-lane product state
//   pool1 -> per-lane RX on each 2-vector factor (LUT by 2 lane bits)
//   conv2 single-qubit layer at factor level; RY(w34)RY(w36), RY(w35)RY(w37) folded
//   CX(0,3),CX(3,6),CX(6,0) folded into expansion indexing:
//     v(b0,b1,b2) = p0(b0^b2) * p1(b0^b1^b2) * p2(b1^b2)   (zero instructions)
//   then param gates + CX(0,6); measure qubit0, ez = 2*P(even)-1.

__device__ __forceinline__ float shx(float v, int m) { return __shfl_xor(v, m, 64); }

__device__ __forceinline__ float2 cmul(float2 a, float2 b) {
  return make_float2(a.x * b.x - a.y * b.y, a.x * b.y + a.y * b.x);
}

// ---- full-state reg-qubit gates ----
template <int TM> __device__ __forceinline__
void ry_r(float (&re)[8], float (&im)[8], float c, float s) {
#pragma unroll
  for (int r0 = 0; r0 < 8; ++r0) if (!(r0 & TM)) {
    const int r1 = r0 | TM;
    float a = re[r0], bb = re[r1];
    re[r0] = c * a - s * bb; re[r1] = s * a + c * bb;
    a = im[r0]; bb = im[r1];
    im[r0] = c * a - s * bb; im[r1] = s * a + c * bb;
  }
}
template <int TM> __device__ __forceinline__
void rz_r(float (&re)[8], float (&im)[8], float c, float s) {
#pragma unroll
  for (int r = 0; r < 8; ++r) {
    const float sg = (r & TM) ? s : -s;
    const float a = re[r], bb = im[r];
    re[r] = c * a - sg * bb;
    im[r] = c * bb + sg * a;
  }
}
template <int CM, int TM> __device__ __forceinline__
void cx_rr(float (&re)[8], float (&im)[8]) {
#pragma unroll
  for (int r0 = 0; r0 < 8; ++r0) if ((r0 & CM) && !(r0 & TM)) {
    const int r1 = r0 | TM;
    float t = re[r0]; re[r0] = re[r1]; re[r1] = t;
    t = im[r0]; im[r0] = im[r1]; im[r1] = t;
  }
}
template <int CM, int TM> __device__ __forceinline__
void crx_rr(float (&re)[8], float (&im)[8], float co, float si) {
#pragma unroll
  for (int r0 = 0; r0 < 8; ++r0) if ((r0 & CM) && !(r0 & TM)) {
    const int r1 = r0 | TM;
    const float r0r = re[r0], r0i = im[r0], r1r = re[r1], r1i = im[r1];
    re[r0] = co * r0r + si * r1i; im[r0] = co * r0i - si * r1r;
    re[r1] = co * r1r + si * r0i; im[r1] = co * r1i - si * r0r;
  }
}

// ---- factor-level single-qubit gates on a complex 2-vector (A,B) ----
__device__ __forceinline__
void ry_f(float2& A, float2& B, float c, float s) {
  const float2 nA = make_float2(c * A.x - s * B.x, c * A.y - s * B.y);
  const float2 nB = make_float2(s * A.x + c * B.x, s * A.y + c * B.y);
  A = nA; B = nB;
}
__device__ __forceinline__
void rz_f(float2& A, float2& B, float c, float s) {
  A = make_float2(c * A.x + s * A.y, c * A.y - s * A.x);   // * e^{-i t/2}
  B = make_float2(c * B.x - s * B.y, c * B.y + s * B.x);   // * e^{+i t/2}
}
__device__ __forceinline__
void rx_f(float2& A, float2& B, float c, float s) {         // pool1 folded RX
  const float2 nA = make_float2(c * A.x + s * B.y, c * A.y - s * B.x);
  const float2 nB = make_float2(c * B.x + s * A.y, c * B.y - s * A.x);
  A = nA; B = nB;
}

__global__ __launch_bounds__(256) void qcnn_fused(const float* __restrict__ x,
                                                  const float* __restrict__ w,
                                                  float* __restrict__ feats) {
  // per-wave LDS regions — no cross-wave sharing, no barriers
  __shared__ float4 tauT[4][9];    // qubit q -> (t0r, t0i, t1r, t1i)
  __shared__ float2 rxT[4][12];    // pool1 RX LUT [axis][2 control bits]
  __shared__ float2 gT[4][16];     // folded gate params (cos, sin)

  const int tid = threadIdx.x;
  const int wv = tid >> 6, lane = tid & 63;
  const unsigned p = blockIdx.x * 4u + wv;           // patch id (grid exact)
  const unsigned b = p / 676u;
  const unsigned rem = p - b * 676u;
  const unsigned i = rem / 26u, j = rem - i * 26u;

  // ---- per-wave table build (lane roles; same-wave DS ordering) ----
  if (lane < 9) {
    const int di = lane / 3, dj = lane - di * 3;
    const float xv = x[b * 784u + (i + di) * 28u + (j + dj)];
    const float ang = fmaf(xv, 3.14159265358979323846f, w[lane]) * 0.5f;
    float s, c; __sincosf(ang, &s, &c);
    float zs, zc; __sincosf(0.5f * w[9 + lane], &zs, &zc);
    tauT[wv][lane] = make_float4(c * zc, -c * zs, s * zc, s * zs);
  } else if (lane < 21) {
    const int k = lane - 9, a = k >> 2, cb = k & 3;
    float th = 0.0f;
    if (cb & 1) th += w[18 + 2 * a];
    if (cb & 2) th += w[19 + 2 * a];
    float s, c; __sincosf(0.5f * th, &s, &c);
    rxT[wv][k] = make_float2(c, s);
  } else if (lane < 37) {
    const int k = lane - 21;
    float th;
    if (k < 10)       th = w[24 + k];            // w24..w33
    else if (k == 10) th = w[34] + w[36];        // folded RY q0
    else if (k == 11) th = w[35] + w[37];        // folded RY q6
    else              th = w[26 + k];            // w38..w41
    float s, c; __sincosf(0.5f * th, &s, &c);
    gT[wv][k] = make_float2(c, s);
  }

  const int l0 = lane & 1, l1 = (lane >> 1) & 1, l2 = (lane >> 2) & 1;
  const int l3 = (lane >> 3) & 1, l4 = (lane >> 4) & 1, l5 = (lane >> 5) & 1;

  float4 tq[9];
#pragma unroll
  for (int q = 0; q < 9; ++q) tq[q] = tauT[wv][q];
  auto tau = [&](int bit, int q) -> float2 {
    const float4 t = tq[q];
    return bit ? make_float2(t.z, t.w) : make_float2(t.x, t.y);
  };

  // post-ring product-state factors (derivation verified R6/R7)
  const int a0 = l5, a1 = l0 ^ l5;
  float2 p00 = cmul(tau(a0, 0), tau(a1, 1));
  float2 p01 = cmul(tau(a0 ^ 1, 0), tau(a1 ^ 1, 1));
  float2 p10 = cmul(tau(l1, 3), tau(l2, 4));
  float2 p11 = cmul(tau(l1 ^ 1, 3), tau(l2 ^ 1, 4));
  float2 p20 = cmul(tau(l3, 6), tau(l4, 7));
  float2 p21 = cmul(tau(l3 ^ 1, 6), tau(l4 ^ 1, 7));
  const float2 T = cmul(cmul(tau(l0 ^ l1, 2), tau(l2 ^ l3, 5)), tau(l4 ^ l5, 8));
  p20 = cmul(p20, T);
  p21 = cmul(p21, T);

  // pool1: per-lane RX on each factor
  {
    const float2 x0 = rxT[wv][lane & 3];
    const float2 x1 = rxT[wv][4 + ((lane >> 2) & 3)];
    const float2 x2 = rxT[wv][8 + ((lane >> 4) & 3)];
    rx_f(p00, p01, x0.x, x0.y);
    rx_f(p10, p11, x1.x, x1.y);
    rx_f(p20, p21, x2.x, x2.y);
  }

  // conv2 single-qubit layer at FACTOR level (w24..w29)
  {
    const float2 g0 = gT[wv][0], g1 = gT[wv][1], g2 = gT[wv][2];
    const float2 g3 = gT[wv][3], g4 = gT[wv][4], g5 = gT[wv][5];
    ry_f(p00, p01, g0.x, g0.y);   // RY q0
    ry_f(p10, p11, g1.x, g1.y);   // RY q3
    ry_f(p20, p21, g2.x, g2.y);   // RY q6
    rz_f(p00, p01, g3.x, g3.y);   // RZ q0
    rz_f(p10, p11, g4.x, g4.y);   // RZ q3
    rz_f(p20, p21, g5.x, g5.y);   // RZ q6
  }

  // expand with CX(0,3),CX(3,6),CX(6,0) FOLDED into the index map:
  //   v(b0,b1,b2) = p0(b0^b2) * p1(b0^b1^b2) * p2(b1^b2)
  float re[8], im[8];
  {
    const float2 q00 = cmul(p00, p10);   // p0(0)p1(0)
    const float2 q01 = cmul(p00, p11);   // p0(0)p1(1)
    const float2 q10 = cmul(p01, p10);   // p0(1)p1(0)
    const float2 q11 = cmul(p01, p11);   // p0(1)p1(1)
    float2 u;
    u = cmul(q00, p20); re[0] = u.x; im[0] = u.y;   // r=0: p0(0)p1(0)p2(0)
    u = cmul(q11, p20); re[1] = u.x; im[1] = u.y;   // r=1: p0(1)p1(1)p2(0)
    u = cmul(q01, p21); re[2] = u.x; im[2] = u.y;   // r=2: p0(0)p1(1)p2(1)
    u = cmul(q10, p21); re[3] = u.x; im[3] = u.y;   // r=3: p0(1)p1(0)p2(1)
    u = cmul(q11, p21); re[4] = u.x; im[4] = u.y;   // r=4: p0(1)p1(1)p2(1)
    u = cmul(q00, p21); re[5] = u.x; im[5] = u.y;   // r=5: p0(0)p1(0)p2(1)
    u = cmul(q10, p20); re[6] = u.x; im[6] = u.y;   // r=6: p0(1)p1(0)p2(0)
    u = cmul(q01, p20); re[7] = u.x; im[7] = u.y;   // r=7: p0(0)p1(1)p2(0)
  }

  // remaining gates (post-CX-trio).
  // DROPPED by commutation algebra (R9):
  //   rz_r<2>(g7)=RZ(q3,w31): diagonal on q3, commutes past CRX(3,0)/CRX(3,6)
  //     (q3=control); q3 idle afterward; q0-only measurement unaffected.
  //   rz_r<4>(gD)=RZ(q6,w39): commutes past CRX(6,0) (q6=control); q6 idle after.
  //   ry_r<1>(gF)=RY(q0,w41): folded into measurement basis below.
  {
    const float2 g6 = gT[wv][6],  g8 = gT[wv][8];
    const float2 g9 = gT[wv][9],  gA = gT[wv][10], gB = gT[wv][11];
    const float2 gC = gT[wv][12], gE = gT[wv][14];
    ry_r<1>(re, im, g6.x, g6.y);         // RY q0 w30
    crx_rr<2, 1>(re, im, g8.x, g8.y);    // CRX(3,0) w32
    crx_rr<2, 4>(re, im, g9.x, g9.y);    // CRX(3,6) w33
    ry_r<1>(re, im, gA.x, gA.y);         // RY q0 (w34+w36)
    ry_r<4>(re, im, gB.x, gB.y);         // RY q6 (w35+w37)
    cx_rr<1, 4>(re, im);                 // CX(0,6)
    rz_r<1>(re, im, gC.x, gC.y);         // RZ q0 w38
    crx_rr<4, 1>(re, im, gE.x, gE.y);    // CRX(6,0) w40
  }

  // <X>,<Y>,<Z> on qubit 0 (reg bit 0); ez = 2*P(even)-1.
  // RY(q0,w41) applied as a Bloch rotation about Y in lane 0:
  //   ex' = cosT*ex + sinT*ez;  ey' = ey;  ez' = cosT*ez - sinT*ex
  // (cosT = c^2-s^2, sinT = 2cs from the stored half-angle pair gF).
  float zr = 0.f, zi = 0.f, pe = 0.f;
#pragma unroll
  for (int r0 = 0; r0 < 8; r0 += 2) {
    const int r1 = r0 + 1;
    zr += re[r0] * re[r1] + im[r0] * im[r1];
    zi += re[r0] * im[r1] - im[r0] * re[r1];
    pe += re[r0] * re[r0] + im[r0] * im[r0];
  }
#pragma unroll
  for (int m = 1; m < 64; m <<= 1) { zr += shx(zr, m); zi += shx(zi, m); pe += shx(pe, m); }

  if (lane == 0) {
    const float2 gF = gT[wv][15];
    const float cT = gF.x * gF.x - gF.y * gF.y;
    const float sT = 2.0f * gF.x * gF.y;
    const float ex = 2.0f * zr;
    const float ez = 2.0f * pe - 1.0f;
    feats[p * 3u + 0u] = cT * ex + sT * ez;
    feats[p * 3u + 1u] = 2.0f * zi;
    feats[p * 3u + 2u] = cT * ez - sT * ex;
  }
}

// out[b,c] = fc_b[c] + dot(feats[b,:], fc_w[c,:]) over 2028 = 507 float4s.
__global__ __launch_bounds__(256) void fc_kernel(const float* __restrict__ feats,
                                                 const float* __restrict__ fc_w,
                                                 const float* __restrict__ fc_b,
                                                 float* __restrict__ out) {
  const int b = blockIdx.x / 10, c = blockIdx.x - b * 10;
  const float4* f  = reinterpret_cast<const float4*>(feats + b * 2028);
  const float4* wr = reinterpret_cast<const float4*>(fc_w + c * 2028);
  float acc = 0.0f;
  for (int k = threadIdx.x; k < 507; k += 256) {
    const float4 fv = f[k], wv4 = wr[k];
    acc += fv.x * wv4.x + fv.y * wv4.y + fv.z * wv4.z + fv.w * wv4.w;
  }
#pragma unroll
  for (int m = 1; m < 64; m <<= 1) acc += __shfl_xor(acc, m, 64);
  __shared__ float sbuf[4];
  const int lane = threadIdx.x & 63, wv = threadIdx.x >> 6;
  if (lane == 0) sbuf[wv] = acc;
  __syncthreads();
  if (threadIdx.x == 0) out[b * 10 + c] = sbuf[0] + sbuf[1] + sbuf[2] + sbuf[3] + fc_b[c];
}

extern "C" void kernel_launch(void* const* d_in, const int* in_sizes, int n_in,
                              void* d_out, int out_size, void* d_ws, size_t ws_size,
                              hipStream_t stream) {
  const float* x    = (const float*)d_in[0];   // (B,1,28,28)
  const float* w    = (const float*)d_in[1];   // (42,)
  const float* fc_w = (const float*)d_in[2];   // (10, 2028)
  const float* fc_b = (const float*)d_in[3];   // (10,)
  float* out = (float*)d_out;                  // (B, 10)

  const int B = in_sizes[0] / 784;             // 8
  const int npatch = B * 676;                  // 5408; divisible by 4

  float* feats = (float*)d_ws;                 // npatch*3 floats, fully written

  qcnn_fused<<<npatch / 4, 256, 0, stream>>>(x, w, feats);
  fc_kernel<<<B * 10, 256, 0, stream>>>(feats, fc_w, fc_b, out);
}

// Round 3
// 65.836 us; speedup vs baseline: 1.1587x; 1.0205x over previous
//
#include <hip/hip_runtime.h>

// One wavefront = one 9-qubit patch circuit. Two-kernel structure:
// feats -> d_ws, then a tiny FC kernel (R8 atomics regression: cross-XCD
// fan-in costs more than a second launch; R7: never grid-fence).
//
// R10 (this round): weight-only gate chains PRE-COMPOSED into 2x2 complex
// matrices by wave 0, shared block-wide via one __syncthreads:
//  - factor stage: RX(pool1,cb) -> RY(conv2) -> RZ(conv2) = ONE matrix
//    (12 variants: 3 axes x 4 control-bit combos).  24 -> 16 instr/factor.
//  - post-expansion: the 8-gate chain is block-diag in q3 (CRX(3,*)
//    controls), and RZ0(w38) commutes past CX(0,6) (q0=control). Per-half
//    q0/q6 chains collapse: M0_0 = RZ(w38)RY(w30+w34+w36),
//    M0_1 = RZ(w38)RY(w34+w36)RX(w32)RY(w30), M6_1 = RY(w35+w37)RX(w33),
//    + RY6(w35+w37) on the b1=0 half + CRX(6,0,w40).  224 -> 96 instr.
// R9 drops stay: RZ(q3,w31), RZ(q6,w39) eliminated by commutation; final
// RY(q0,w41) folded into the measurement basis in lane 0.
//
// Qubit -> bit remap:
//   qubit 0 -> reg bit 0  qubit 3 -> reg bit 1  qubit 6 -> reg bit 2
//   qubit 1 -> lane bit 0  qubit 2 -> lane bit 1  qubit 4 -> lane bit 2
//   qubit 5 -> lane bit 3  qubit 7 -> lane bit 4  qubit 8 -> lane bit 5
//
// Pipeline (pieces correctness-proven R6-R9):
//   enc RY + conv1 RY -> per-qubit (c,s); conv1 RZ folds into tau_q(b)
//   ring CNOT eliminated analytically -> per-lane product state
//   pool1+conv2 -> one 2x2 matrix per factor (this round)
//   CX(0,3),CX(3,6),CX(6,0) folded into expansion indexing:
//     v(b0,b1,b2) = p0(b0^b2) * p1(b0^b1^b2) * p2(b1^b2)
//   post gates via per-q3-half composed matrices; measure qubit0.

__device__ __forceinline__ float shx(float v, int m) { return __shfl_xor(v, m, 64); }

__device__ __forceinline__ float2 cmul(float2 a, float2 b) {
  return make_float2(a.x * b.x - a.y * b.y, a.x * b.y + a.y * b.x);
}

// general 2x2 complex matrix on a factor 2-vector; rows packed as
// float4 = (m00r, m00i, m01r, m01i) / (m10r, m10i, m11r, m11i)
__device__ __forceinline__
void g2_f(float2& A, float2& B, float4 R0, float4 R1) {
  const float2 nA = make_float2(R0.x*A.x - R0.y*A.y + R0.z*B.x - R0.w*B.y,
                                R0.x*A.y + R0.y*A.x + R0.z*B.y + R0.w*B.x);
  const float2 nB = make_float2(R1.x*A.x - R1.y*A.y + R1.z*B.x - R1.w*B.y,
                                R1.x*A.y + R1.y*A.x + R1.z*B.y + R1.w*B.x);
  A = nA; B = nB;
}

// general 2x2 on a register-state pair (compile-time indices)
template <int RA, int RB> __device__ __forceinline__
void g2_r(float (&re)[8], float (&im)[8], float4 R0, float4 R1) {
  const float ar = re[RA], ai = im[RA], br = re[RB], bi = im[RB];
  re[RA] = R0.x*ar - R0.y*ai + R0.z*br - R0.w*bi;
  im[RA] = R0.x*ai + R0.y*ar + R0.z*bi + R0.w*br;
  re[RB] = R1.x*ar - R1.y*ai + R1.z*br - R1.w*bi;
  im[RB] = R1.x*ai + R1.y*ar + R1.z*bi + R1.w*br;
}
template <int RA, int RB> __device__ __forceinline__
void ry_pair(float (&re)[8], float (&im)[8], float c, float s) {
  float a = re[RA], bb = re[RB];
  re[RA] = c*a - s*bb; re[RB] = s*a + c*bb;
  a = im[RA]; bb = im[RB];
  im[RA] = c*a - s*bb; im[RB] = s*a + c*bb;
}
template <int CM, int TM> __device__ __forceinline__
void cx_rr(float (&re)[8], float (&im)[8]) {
#pragma unroll
  for (int r0 = 0; r0 < 8; ++r0) if ((r0 & CM) && !(r0 & TM)) {
    const int r1 = r0 | TM;
    float t = re[r0]; re[r0] = re[r1]; re[r1] = t;
    t = im[r0]; im[r0] = im[r1]; im[r1] = t;
  }
}
template <int CM, int TM> __device__ __forceinline__
void crx_rr(float (&re)[8], float (&im)[8], float co, float si) {
#pragma unroll
  for (int r0 = 0; r0 < 8; ++r0) if ((r0 & CM) && !(r0 & TM)) {
    const int r1 = r0 | TM;
    const float r0r = re[r0], r0i = im[r0], r1r = re[r1], r1i = im[r1];
    re[r0] = co * r0r + si * r1i; im[r0] = co * r0i - si * r1r;
    re[r1] = co * r1r + si * r0i; im[r1] = co * r1i - si * r0r;
  }
}

__global__ __launch_bounds__(256) void qcnn_fused(const float* __restrict__ x,
                                                  const float* __restrict__ w,
                                                  float* __restrict__ feats) {
  __shared__ float4 tauT[4][9];  // per-wave: qubit q -> (t0r, t0i, t1r, t1i)
  __shared__ float4 matT[30];    // [0..23] factor mats (12 x 2 rows); [24..29] M0_0, M0_1, M6_1
  __shared__ float2 sT[3];       // 0: (c,s) w40/2 CRX(6,0); 1: w41/2 fold; 2: (w35+w37)/2 RY6

  const int tid = threadIdx.x;
  const int wv = tid >> 6, lane = tid & 63;
  const unsigned p = blockIdx.x * 4u + wv;           // patch id (grid exact)
  const unsigned b = p / 676u;
  const unsigned rem = p - b * 676u;
  const unsigned i = rem / 26u, j = rem - i * 26u;

  // ---- per-wave patch-dependent table (all waves) ----
  if (lane < 9) {
    const int di = lane / 3, dj = lane - di * 3;
    const float xv = x[b * 784u + (i + di) * 28u + (j + dj)];
    const float ang = fmaf(xv, 3.14159265358979323846f, w[lane]) * 0.5f;
    float s, c; __sincosf(ang, &s, &c);
    float zs, zc; __sincosf(0.5f * w[9 + lane], &zs, &zc);
    tauT[wv][lane] = make_float4(c * zc, -c * zs, s * zc, s * zs);
  }

  // ---- weight-only tables: built ONCE by wave 0, shared block-wide ----
  if (wv == 0) {
    const bool isF = (lane >= 9 && lane < 21);   // 12 factor matrices
    const bool isM = (lane >= 24 && lane < 27);  // 3 post-expansion matrices
    if (isF || isM) {
      // compose M = RZ(z) * RY(c) * RX(bb) * RY(a)   (all half-angle convention)
      float a = 0.f, bb = 0.f, c = 0.f, z = 0.f;
      int dst;
      if (isF) {
        const int k = lane - 9, ax = k >> 2, cb2 = k & 3;
        bb = ((cb2 & 1) ? w[18 + 2 * ax] : 0.f) + ((cb2 & 2) ? w[19 + 2 * ax] : 0.f);
        c = w[24 + ax]; z = w[27 + ax];
        dst = k;
      } else {
        const int m = lane - 24;
        if (m == 0)      { a = w[30] + w[34] + w[36]; z = w[38]; }
        else if (m == 1) { a = w[30]; bb = w[32]; c = w[34] + w[36]; z = w[38]; }
        else             { bb = w[33]; c = w[35] + w[37]; }
        dst = 12 + m;
      }
      float sa, ca, sb, cb, sc, cc, sz, cz;
      __sincosf(0.5f * a,  &sa, &ca);
      __sincosf(0.5f * bb, &sb, &cb);
      __sincosf(0.5f * c,  &sc, &cc);
      __sincosf(0.5f * z,  &sz, &cz);
      // A = RX(bb)*RY(a);  RX = [[cb,-i sb],[-i sb,cb]], RY = [[ca,-sa],[sa,ca]]
      const float A00r =  cb * ca, A00i = -sb * sa;
      const float A01r = -cb * sa, A01i = -sb * ca;
      const float A10r =  cb * sa, A10i = -sb * ca;
      const float A11r =  cb * ca, A11i =  sb * sa;
      // B = RY(c)*A (real coefficients)
      const float B00r = cc * A00r - sc * A10r, B00i = cc * A00i - sc * A10i;
      const float B01r = cc * A01r - sc * A11r, B01i = cc * A01i - sc * A11i;
      const float B10r = sc * A00r + cc * A10r, B10i = sc * A00i + cc * A10i;
      const float B11r = sc * A01r + cc * A11r, B11i = sc * A01i + cc * A11i;
      // M = RZ(z)*B: row0 *= e^{-iz/2}, row1 *= e^{+iz/2}
      matT[dst * 2 + 0] = make_float4(cz * B00r + sz * B00i, cz * B00i - sz * B00r,
                                      cz * B01r + sz * B01i, cz * B01i - sz * B01r);
      matT[dst * 2 + 1] = make_float4(cz * B10r - sz * B10i, cz * B10i + sz * B10r,
                                      cz * B11r - sz * B11i, cz * B11i + sz * B11r);
    } else if (lane >= 27 && lane < 30) {
      const int k = lane - 27;
      const float th = (k == 0) ? w[40] : (k == 1) ? w[41] : (w[35] + w[37]);
      float s, c; __sincosf(0.5f * th, &s, &c);
      sT[k] = make_float2(c, s);
    }
  }
  __syncthreads();

  const int l0 = lane & 1, l1 = (lane >> 1) & 1, l2 = (lane >> 2) & 1;
  const int l3 = (lane >> 3) & 1, l4 = (lane >> 4) & 1, l5 = (lane >> 5) & 1;

  float4 tq[9];
#pragma unroll
  for (int q = 0; q < 9; ++q) tq[q] = tauT[wv][q];
  auto tau = [&](int bit, int q) -> float2 {
    const float4 t = tq[q];
    return bit ? make_float2(t.z, t.w) : make_float2(t.x, t.y);
  };

  // post-ring product-state factors (derivation verified R6/R7)
  const int a0 = l5, a1 = l0 ^ l5;
  float2 p00 = cmul(tau(a0, 0), tau(a1, 1));
  float2 p01 = cmul(tau(a0 ^ 1, 0), tau(a1 ^ 1, 1));
  float2 p10 = cmul(tau(l1, 3), tau(l2, 4));
  float2 p11 = cmul(tau(l1 ^ 1, 3), tau(l2 ^ 1, 4));
  float2 p20 = cmul(tau(l3, 6), tau(l4, 7));
  float2 p21 = cmul(tau(l3 ^ 1, 6), tau(l4 ^ 1, 7));
  const float2 T = cmul(cmul(tau(l0 ^ l1, 2), tau(l2 ^ l3, 5)), tau(l4 ^ l5, 8));
  p20 = cmul(p20, T);
  p21 = cmul(p21, T);

  // pool1 + conv2 as ONE pre-composed 2x2 per factor (LUT by control bits)
  {
    const int i0 = (lane & 3) << 1;
    const int i1 = (4 + ((lane >> 2) & 3)) << 1;
    const int i2 = (8 + ((lane >> 4) & 3)) << 1;
    g2_f(p00, p01, matT[i0], matT[i0 | 1]);
    g2_f(p10, p11, matT[i1], matT[i1 | 1]);
    g2_f(p20, p21, matT[i2], matT[i2 | 1]);
  }

  // expand with CX(0,3),CX(3,6),CX(6,0) FOLDED into the index map:
  //   v(b0,b1,b2) = p0(b0^b2) * p1(b0^b1^b2) * p2(b1^b2)
  float re[8], im[8];
  {
    const float2 q00 = cmul(p00, p10);
    const float2 q01 = cmul(p00, p11);
    const float2 q10 = cmul(p01, p10);
    const float2 q11 = cmul(p01, p11);
    float2 u;
    u = cmul(q00, p20); re[0] = u.x; im[0] = u.y;
    u = cmul(q11, p20); re[1] = u.x; im[1] = u.y;
    u = cmul(q01, p21); re[2] = u.x; im[2] = u.y;
    u = cmul(q10, p21); re[3] = u.x; im[3] = u.y;
    u = cmul(q11, p21); re[4] = u.x; im[4] = u.y;
    u = cmul(q00, p21); re[5] = u.x; im[5] = u.y;
    u = cmul(q10, p20); re[6] = u.x; im[6] = u.y;
    u = cmul(q01, p20); re[7] = u.x; im[7] = u.y;
  }

  // post-expansion gates via per-q3-half composed matrices.
  // b1=0 states {0,1,4,5}: q0-pairs (0,1),(4,5) get M0_0; q6-pairs (0,4),(1,5) get RY6.
  // b1=1 states {2,3,6,7}: q0-pairs (2,3),(6,7) get M0_1; q6-pairs (2,6),(3,7) get M6_1.
  // Then CX(0,6) (register rename) and CRX(6,0,w40) on pairs (4,5),(6,7).
  {
    const float4 A0 = matT[24], A1 = matT[25];
    const float4 B0 = matT[26], B1 = matT[27];
    const float4 C0 = matT[28], C1 = matT[29];
    const float2 s2 = sT[2];
    g2_r<0, 1>(re, im, A0, A1); g2_r<4, 5>(re, im, A0, A1);
    g2_r<2, 3>(re, im, B0, B1); g2_r<6, 7>(re, im, B0, B1);
    ry_pair<0, 4>(re, im, s2.x, s2.y); ry_pair<1, 5>(re, im, s2.x, s2.y);
    g2_r<2, 6>(re, im, C0, C1); g2_r<3, 7>(re, im, C0, C1);
    cx_rr<1, 4>(re, im);                 // CX(0,6)
    const float2 sE = sT[0];
    crx_rr<4, 1>(re, im, sE.x, sE.y);    // CRX(6,0) w40
  }

  // <X>,<Y>,<Z> on qubit 0; ez = 2*P(even)-1.
  // RY(q0,w41) applied as a Bloch rotation about Y in lane 0.
  float zr = 0.f, zi = 0.f, pe = 0.f;
#pragma unroll
  for (int r0 = 0; r0 < 8; r0 += 2) {
    const int r1 = r0 + 1;
    zr += re[r0] * re[r1] + im[r0] * im[r1];
    zi += re[r0] * im[r1] - im[r0] * re[r1];
    pe += re[r0] * re[r0] + im[r0] * im[r0];
  }
#pragma unroll
  for (int m = 1; m < 64; m <<= 1) { zr += shx(zr, m); zi += shx(zi, m); pe += shx(pe, m); }

  if (lane == 0) {
    const float2 gF = sT[1];
    const float cT = gF.x * gF.x - gF.y * gF.y;
    const float sTT = 2.0f * gF.x * gF.y;
    const float ex = 2.0f * zr;
    const float ez = 2.0f * pe - 1.0f;
    feats[p * 3u + 0u] = cT * ex + sTT * ez;
    feats[p * 3u + 1u] = 2.0f * zi;
    feats[p * 3u + 2u] = cT * ez - sTT * ex;
  }
}

// out[b,c] = fc_b[c] + dot(feats[b,:], fc_w[c,:]) over 2028 = 507 float4s.
__global__ __launch_bounds__(256) void fc_kernel(const float* __restrict__ feats,
                                                 const float* __restrict__ fc_w,
                                                 const float* __restrict__ fc_b,
                                                 float* __restrict__ out) {
  const int b = blockIdx.x / 10, c = blockIdx.x - b * 10;
  const float4* f  = reinterpret_cast<const float4*>(feats + b * 2028);
  const float4* wr = reinterpret_cast<const float4*>(fc_w + c * 2028);
  float acc = 0.0f;
  for (int k = threadIdx.x; k < 507; k += 256) {
    const float4 fv = f[k], wv4 = wr[k];
    acc += fv.x * wv4.x + fv.y * wv4.y + fv.z * wv4.z + fv.w * wv4.w;
  }
#pragma unroll
  for (int m = 1; m < 64; m <<= 1) acc += __shfl_xor(acc, m, 64);
  __shared__ float sbuf[4];
  const int lane = threadIdx.x & 63, wv = threadIdx.x >> 6;
  if (lane == 0) sbuf[wv] = acc;
  __syncthreads();
  if (threadIdx.x == 0) out[b * 10 + c] = sbuf[0] + sbuf[1] + sbuf[2] + sbuf[3] + fc_b[c];
}

extern "C" void kernel_launch(void* const* d_in, const int* in_sizes, int n_in,
                              void* d_out, int out_size, void* d_ws, size_t ws_size,
                              hipStream_t stream) {
  const float* x    = (const float*)d_in[0];   // (B,1,28,28)
  const float* w    = (const float*)d_in[1];   // (42,)
  const float* fc_w = (const float*)d_in[2];   // (10, 2028)
  const float* fc_b = (const float*)d_in[3];   // (10,)
  float* out = (float*)d_out;                  // (B, 10)

  const int B = in_sizes[0] / 784;             // 8
  const int npatch = B * 676;                  // 5408; divisible by 4

  float* feats = (float*)d_ws;                 // npatch*3 floats, fully written

  qcnn_fused<<<npatch / 4, 256, 0, stream>>>(x, w, feats);
  fc_kernel<<<B * 10, 256, 0, stream>>>(feats, fc_w, fc_b, out);
}